// Round 6
// baseline (245.728 us; speedup 1.0000x reference)
//
#include <hip/hip_runtime.h>

// ---------- problem constants ----------
#define BATCH   16
#define LIN     320000
#define LP      322048          // LIN + 2048 (reflect pad 1024 each side)
#define TFR     626             // frames per batch
#define MTOT    (BATCH*TFR)     // 10016
#define KD      2048            // N_FFT
#define KOUT    1025            // N_FFT/2+1
// packed cols: n<1025 -> real k=n ; n in [1025,2048) -> imag k=n-1024 (1..1023)
// imag k=0 and k=1024 are analytically ~0 -> written as zeros in prep
#define IMAG_OFF ((long)MTOT*KOUT)   // 10266400
#define BK 32

typedef __attribute__((ext_vector_type(8))) short short8;
typedef __attribute__((ext_vector_type(4))) float float4v;
typedef unsigned short ushort_t;

#define XP_BLOCKS   ((BATCH*LP)/2048)        // 2516 (8 elems/thread)
#define WBT_BLOCKS  ((KD/64)*(KD/64))        // 1024 (64x64 tiles)
#define ZB_BLOCKS   ((2*MTOT+255)/256)       // 79  (imag k=0,1024 zeros)

static __device__ __forceinline__ ushort_t f32_to_bf16(float f) {
    union { float f; unsigned u; } un; un.f = f;
    unsigned r = un.u + 0x7fffu + ((un.u >> 16) & 1u);   // RNE
    return (ushort_t)(r >> 16);
}

static __device__ __forceinline__ void async_copy16(const void* g, void* l) {
    __builtin_amdgcn_global_load_lds(
        (const __attribute__((address_space(1))) void*)g,
        (__attribute__((address_space(3))) void*)l, 16, 0, 0);
}

// ---------- fused prep: xp build | W^T pack | imag edge-column zeros --------
__global__ void prep(const float* __restrict__ x,
                     const float* __restrict__ wr,
                     const float* __restrict__ wi,
                     ushort_t* __restrict__ xp,
                     ushort_t* __restrict__ wbt,
                     float* __restrict__ out) {
    __shared__ ushort_t tile[64][65];
    const int blk = blockIdx.x;

    if (blk < XP_BLOCKS) {
        // reflect-pad fp32 x -> bf16 xp, 8 elements per thread
        int i0 = blk * 2048 + threadIdx.x * 8;
        int b  = i0 / LP;
        int p0 = i0 - b * LP;
        short8 v;
        if (p0 >= 1024 && p0 + 8 <= 1024 + LIN) {        // interior fast path
            const float* src = x + b * LIN + (p0 - 1024);
            float4v u0 = *(const float4v*)src;
            float4v u1 = *(const float4v*)(src + 4);
#pragma unroll
            for (int e = 0; e < 4; ++e) { v[e] = (short)f32_to_bf16(u0[e]); v[4+e] = (short)f32_to_bf16(u1[e]); }
        } else {
#pragma unroll
            for (int e = 0; e < 8; ++e) {
                int i = i0 + e;
                int bb = i / LP;
                int j = (i - bb * LP) - 1024;
                if (j < 0) j = -j;
                else if (j >= LIN) j = 2 * LIN - 2 - j;
                v[e] = (short)f32_to_bf16(x[bb * LIN + j]);
            }
        }
        *(short8*)(xp + i0) = v;
    } else if (blk < XP_BLOCKS + WBT_BLOCKS) {
        // pack W^T n-major bf16 via 64x64 LDS transpose tile
        int t  = blk - XP_BLOCKS;
        int n0 = (t & 31) * 64;
        int k0 = (t >> 5) * 64;
        int tx = threadIdx.x & 63;
        int ty = threadIdx.x >> 6;               // 0..3
        int n  = n0 + tx;
#pragma unroll
        for (int i = 0; i < 16; ++i) {
            int k = k0 + ty + i * 4;
            float v = (n < KOUT) ? wr[k * KOUT + n] : wi[k * KOUT + (n - 1024)];
            tile[ty + i * 4][tx] = f32_to_bf16(v);
        }
        __syncthreads();
#pragma unroll
        for (int i = 0; i < 16; ++i) {
            int row = ty + i * 4;                // n within tile
            wbt[(n0 + row) * KD + k0 + tx] = tile[tx][row];
        }
    } else {
        // imag k=0 and k=1024 columns are ~1e-12 -> exact zeros
        int idx = (blk - XP_BLOCKS - WBT_BLOCKS) * 256 + threadIdx.x;
        if (idx < 2 * MTOT) {
            int m = (idx < MTOT) ? idx : (idx - MTOT);
            int k = (idx < MTOT) ? 0 : 1024;
            out[IMAG_OFF + (long)m * KOUT + k] = 0.f;
        }
    }
}

// ---------- main GEMM: 128x128 tile, BK=32, DOUBLE-BUFFERED LDS -------------
// One barrier per K-iteration; prefetch of tile k+1 is issued right after the
// barrier and stays in flight across the whole compute phase of tile k. The
// vmcnt(0) drain at the next barrier lands after ~16 MFMA of cover.
__global__ __launch_bounds__(256) void stft_gemm(const ushort_t* __restrict__ xp,
                                                 const ushort_t* __restrict__ wbt,
                                                 float* __restrict__ out) {
    __shared__ __align__(16) ushort_t As[2][128 * BK];   // 2 x 8 KB
    __shared__ __align__(16) ushort_t Bs[2][128 * BK];   // 2 x 8 KB

    const int tid = threadIdx.x;
    // XCD-aware mapping: XCD j owns n-tiles {2j,2j+1}; sweeps m with both
    // n-tiles adjacent -> wbt slice (1 MB) stays L2-resident per XCD
    const int f   = blockIdx.x;            // 0..1263
    const int xcd = f & 7;
    const int w   = f >> 3;                // 0..157
    const int n0  = (2 * xcd + (w & 1)) * 128;
    const int m0  = (w >> 1) * 128;        // 0..78

    // staging: slot s = j*256+tid -> row=s>>2, phys granule=s&3,
    // logical granule g = (s&3) ^ (row&3); source k-offset = g*8
    int baseA[2], baseB[2];
#pragma unroll
    for (int j = 0; j < 2; ++j) {
        int slot = j * 256 + tid;
        int row  = slot >> 2;
        int g    = (slot & 3) ^ (row & 3);
        int m = m0 + row; if (m > MTOT - 1) m = MTOT - 1;   // clamp; stores guarded
        int b = m / TFR;
        int t = m - b * TFR;
        baseA[j] = b * LP + t * 512 + g * 8;
        baseB[j] = (n0 + row) * KD + g * 8;                 // n0+row < 2048 always
    }

    const int wave = tid >> 6;
    const int lane = tid & 63;
    const int wm = (wave >> 1) * 64;
    const int wn = (wave & 1) * 64;
    const int lm = lane & 15;
    const int quad = lane >> 4;

    // LDS read offsets (elements), fixed per lane: row*BK + (quad^(row&3))*8
    int offA[4], offB[4];
#pragma unroll
    for (int i = 0; i < 4; ++i) {
        int rowA = wm + i * 16 + lm;
        offA[i] = rowA * BK + (quad ^ (rowA & 3)) * 8;
        int rowB = wn + i * 16 + lm;
        offB[i] = rowB * BK + (quad ^ (rowB & 3)) * 8;
    }

    float4v acc[4][4];
#pragma unroll
    for (int mi = 0; mi < 4; ++mi)
#pragma unroll
        for (int ni = 0; ni < 4; ++ni)
            acc[mi][ni] = (float4v){0.f, 0.f, 0.f, 0.f};

#define ISSUE(buf, k0)                                                          \
    {                                                                           \
        _Pragma("unroll")                                                       \
        for (int j = 0; j < 2; ++j) {                                           \
            async_copy16(xp + baseA[j] + (k0), (char*)As[buf] + (j*256+tid)*16);\
            async_copy16(wbt + baseB[j] + (k0), (char*)Bs[buf] + (j*256+tid)*16);\
        }                                                                       \
    }

#define COMPUTE(buf)                                                            \
    {                                                                           \
        short8 af[4], bf[4];                                                    \
        _Pragma("unroll")                                                       \
        for (int i = 0; i < 4; ++i) {                                           \
            af[i] = *(const short8*)&As[buf][offA[i]];                          \
            bf[i] = *(const short8*)&Bs[buf][offB[i]];                          \
        }                                                                       \
        _Pragma("unroll")                                                       \
        for (int mi = 0; mi < 4; ++mi)                                          \
            _Pragma("unroll")                                                   \
            for (int ni = 0; ni < 4; ++ni)                                      \
                acc[mi][ni] = __builtin_amdgcn_mfma_f32_16x16x32_bf16(          \
                    af[mi], bf[ni], acc[mi][ni], 0, 0, 0);                      \
    }

    ISSUE(0, 0);
    for (int it = 0; it < KD / BK; it += 2) {      // 64 iters, unrolled x2
        __syncthreads();                           // drains prefetch -> buf0
        if (it + 1 < KD / BK) ISSUE(1, (it + 1) * BK);
        COMPUTE(0);                                // covers buf1 prefetch
        __syncthreads();                           // drains prefetch -> buf1
        if (it + 2 < KD / BK) ISSUE(0, (it + 2) * BK);
        COMPUTE(1);                                // covers buf0 prefetch
    }
#undef ISSUE
#undef COMPUTE

    // epilogue: C/D layout col=lane&15 (n), row=quad*4+reg (m); fp32 out
#pragma unroll
    for (int mi = 0; mi < 4; ++mi) {
#pragma unroll
        for (int ni = 0; ni < 4; ++ni) {
            int n = n0 + wn + ni * 16 + lm;           // < 2048 always
            long nbase = (n < KOUT) ? (long)n : (IMAG_OFF + (n - 1024));
#pragma unroll
            for (int rg = 0; rg < 4; ++rg) {
                int m = m0 + wm + mi * 16 + quad * 4 + rg;
                if (m < MTOT)
                    out[nbase + (long)m * KOUT] = acc[mi][ni][rg];
            }
        }
    }
}

extern "C" void kernel_launch(void* const* d_in, const int* in_sizes, int n_in,
                              void* d_out, int out_size, void* d_ws, size_t ws_size,
                              hipStream_t stream) {
    const float* x  = (const float*)d_in[0];     // fp32 (16, 320000)
    const float* wr = (const float*)d_in[1];     // fp32 (2048, 1025)
    const float* wi = (const float*)d_in[2];     // fp32 (2048, 1025)
    float* out = (float*)d_out;                  // fp32, 2*16*626*1025

    ushort_t* xp  = (ushort_t*)d_ws;             // 16*322048 bf16 = 10.3 MB
    ushort_t* wbt = xp + BATCH * LP;             // 2048*2048 bf16 =  8.4 MB

    prep<<<XP_BLOCKS + WBT_BLOCKS + ZB_BLOCKS, 256, 0, stream>>>(x, wr, wi, xp, wbt, out);

    stft_gemm<<<79 * 16, 256, 0, stream>>>(xp, wbt, out);   // 1264 blocks, XCD-swizzled
}